// Round 10
// baseline (2280.215 us; speedup 1.0000x reference)
//
#include <hip/hip_runtime.h>
#include <math.h>

// B = T = 1000, N = 128, D = 64. All batch rows identical -> simulate one row
// in f64, broadcast. Round 10: first counter-driven optimization.
//   sim (was 1050us, latency-bound, VALUBusy ~10% of its CU):
//     - lane l owns neurons 2l/2l+1 (pairs adjacent): ds_read_b64 gather,
//       dwordx4 x-loads, 2x8B output stores
//     - two-batch software-pipelined sparse gather (hide LDS latency)
//     - tree reduction within batch (depth 3); syn/10 -> syn*0.1 (no f64 div)
//     - double-buffered 8-step x prefetch
//     (order-of-summation + div->mul: ~1e-16 perturbations, ~1e-10 after
//      chaotic amplification -- measured f32-ref gap is 0.0625, safe)
//   bcast (was ~950us inferred = 1.1 TB/s, dispatch-bound at 32k tiny blocks):
//     - 1000 blocks; each thread reads row-0 vf4 once, streams 125 rows of
//       nontemporal stores.

#define XCHUNK 8   // input-current register prefetch depth (steps)

typedef float  vf4 __attribute__((ext_vector_type(4)));
typedef float  vf2 __attribute__((ext_vector_type(2)));
typedef double vd2 __attribute__((ext_vector_type(2)));

// ---------------------------------------------------------------------------
// Kernel 1: inp_cur[t][n] = sum_d sig[t][d] * win[d][n]  (float64 accumulate)
// UNCHANGED (bit-exact reproducibility).
// ---------------------------------------------------------------------------
__global__ void inpcur_kernel(const float* __restrict__ sig,
                              const float* __restrict__ win,
                              double* __restrict__ inp_cur,
                              int D, int N) {
    const int t = blockIdx.x;
    const int n = threadIdx.x;
    const float* srow = sig + (size_t)t * D;
    double acc = 0.0;
    for (int d = 0; d < D; ++d)
        acc += (double)srow[d] * (double)win[(size_t)d * N + n];
    inp_cur[(size_t)t * N + n] = acc;
}

// ---------------------------------------------------------------------------
// Kernel 2: 1000-step LIF scan, ONE wave. Lane l owns neurons 2l and 2l+1.
// ---------------------------------------------------------------------------
__global__ __launch_bounds__(64, 1) void sim_kernel(
    const double* __restrict__ inp_cur,
    const float* __restrict__ wrec,
    float* __restrict__ spk_out,    // row 0 of spikes region
    float* __restrict__ mem_out,    // row 0 of membrane region
    float* __restrict__ trace_out,  // row 0 of trace region
    int nt) {
    __shared__ float lds_w[128 * 128];  // 64 KiB: wrec row-major

    const int l = threadIdx.x;  // lane 0..63

    __builtin_amdgcn_s_setprio(3);

    // Stage wrec into LDS (vectorized, coalesced; same-wave RAW -> waitcnt).
    {
        const vf4* src = (const vf4*)wrec;
        vf4* dst = (vf4*)lds_w;
        for (int i = 0; i < 64; ++i)
            dst[i * 64 + l] = src[i * 64 + l];
    }
    // w2[k*64 + l] = {wrec[k][2l], wrec[k][2l+1]}  (one ds_read_b64)
    const vf2* w2 = (const vf2*)lds_w;

    double mem0 = 0.0, syn0 = 0.0, trc0 = 0.0, refr0 = 0.0, rec0 = 0.0;
    double mem1 = 0.0, syn1 = 0.0, trc1 = 0.0, refr1 = 0.0, rec1 = 0.0;

    vd2 xa[XCHUNK], xb[XCHUNK];  // double-buffered input currents

#define LDX(t) (((const vd2*)(inp_cur + (size_t)(t) * 128))[l])

// Drain up to 8 spiked rows from (mA: even rows, mB: odd rows), ascending
// evens then ascending odds. Pad slots: kk=0, vv=false (adds exact +0.0).
#define POP8(kk, vv)                                                     \
    do {                                                                 \
        _Pragma("unroll") for (int j = 0; j < 8; ++j) {                  \
            vv[j] = (mA | mB) != 0ull;                                   \
            if (mA)      { kk[j] = 2 * (int)__builtin_ctzll(mA);     mA &= mA - 1ull; } \
            else if (mB) { kk[j] = 2 * (int)__builtin_ctzll(mB) + 1; mB &= mB - 1ull; } \
            else kk[j] = 0;                                              \
        }                                                                \
    } while (0)

#define ISSUE8(kk, w)                                                    \
    do {                                                                 \
        _Pragma("unroll") for (int j = 0; j < 8; ++j)                    \
            w[j] = w2[kk[j] * 64 + l];                                   \
    } while (0)

// Tree-reduce one batch into add0/add1 (cndmask on f32, then convert).
#define CONSUME8(w, vv)                                                  \
    do {                                                                 \
        double e0[8], e1[8];                                             \
        _Pragma("unroll") for (int j = 0; j < 8; ++j) {                  \
            float f0 = vv[j] ? w[j].x : 0.0f;                            \
            float f1 = vv[j] ? w[j].y : 0.0f;                            \
            e0[j] = (double)f0;                                          \
            e1[j] = (double)f1;                                          \
        }                                                                \
        add0 += ((e0[0] + e0[1]) + (e0[2] + e0[3])) +                    \
                ((e0[4] + e0[5]) + (e0[6] + e0[7]));                     \
        add1 += ((e1[0] + e1[1]) + (e1[2] + e1[3])) +                    \
                ((e1[4] + e1[5]) + (e1[6] + e1[7]));                     \
    } while (0)

    auto STEP = [&](int t, vd2 x) {
        syn0 = syn0 * (1.0 - 1.0 / 5.0) + x.x + rec0;
        mem0 = mem0 * (1.0 - 1.0 / 10.0) + syn0 * 0.1;
        if (refr0 > 0.0) mem0 = 0.0;
        refr0 = refr0 - 1.0;
        if (refr0 < 0.0) refr0 = 0.0;
        const bool sp0 = mem0 > 1.0;

        syn1 = syn1 * (1.0 - 1.0 / 5.0) + x.y + rec1;
        mem1 = mem1 * (1.0 - 1.0 / 10.0) + syn1 * 0.1;
        if (refr1 > 0.0) mem1 = 0.0;
        refr1 = refr1 - 1.0;
        if (refr1 < 0.0) refr1 = 0.0;
        const bool sp1 = mem1 > 1.0;

        // Wave-uniform spike masks in SGPRs. bit l of mA -> row 2l (even),
        // bit l of mB -> row 2l+1 (odd).
        unsigned long long mA = __ballot(sp0);
        unsigned long long mB = __ballot(sp1);
        const bool anysp = (mA | mB) != 0ull;

        if (sp0) { mem0 = 0.0; refr0 += 2.0; }
        trc0 = trc0 * 0.95 + (sp0 ? 1.0 : 0.0);
        if (sp1) { mem1 = 0.0; refr1 += 2.0; }
        trc1 = trc1 * 0.95 + (sp1 ? 1.0 : 0.0);

        double add0 = 0.0, add1 = 0.0;
        int  kkA[8], kkB[8];
        bool vvA[8], vvB[8];
        vf2  wA[8],  wB[8];

        // Issue first gather batch ASAP, then overlap its LDS latency with
        // the output stores (8B/lane, coalesced).
        if (anysp) { POP8(kkA, vvA); ISSUE8(kkA, wA); }

        {
            vf2 sv; sv.x = sp0 ? 1.0f : 0.0f; sv.y = sp1 ? 1.0f : 0.0f;
            ((vf2*)(spk_out + (size_t)t * 128))[l] = sv;
            vf2 mv; mv.x = (float)mem0; mv.y = (float)mem1;
            ((vf2*)(mem_out + (size_t)t * 128))[l] = mv;
        }

        // Two-batch software pipeline: issue batch N+1 before consuming N,
        // so each batch's LDS latency hides under the previous one's adds.
        if (anysp) {
            for (;;) {
                const bool moreB = (mA | mB) != 0ull;
                if (moreB) { POP8(kkB, vvB); ISSUE8(kkB, wB); }
                CONSUME8(wA, vvA);
                if (!moreB) break;
                const bool moreA = (mA | mB) != 0ull;
                if (moreA) { POP8(kkA, vvA); ISSUE8(kkA, wA); }
                CONSUME8(wB, vvB);
                if (!moreA) break;
            }
        }
        rec0 = rec0 * 0.95 + add0;
        rec1 = rec1 * 0.95 + add1;
    };

    // Prologue: load first half-chunk.
    #pragma unroll
    for (int s = 0; s < XCHUNK; ++s)
        if (s < nt) xa[s] = LDX(s);

    for (int t0 = 0; t0 < nt; t0 += 2 * XCHUNK) {
        #pragma unroll
        for (int s = 0; s < XCHUNK; ++s)
            if (t0 + XCHUNK + s < nt) xb[s] = LDX(t0 + XCHUNK + s);
        #pragma unroll
        for (int s = 0; s < XCHUNK; ++s)
            if (t0 + s < nt) STEP(t0 + s, xa[s]);
        #pragma unroll
        for (int s = 0; s < XCHUNK; ++s)
            if (t0 + 2 * XCHUNK + s < nt) xa[s] = LDX(t0 + 2 * XCHUNK + s);
        #pragma unroll
        for (int s = 0; s < XCHUNK; ++s)
            if (t0 + XCHUNK + s < nt) STEP(t0 + XCHUNK + s, xb[s]);
    }

    vf2 tv; tv.x = (float)trc0; tv.y = (float)trc1;
    ((vf2*)trace_out)[l] = tv;

#undef LDX
#undef POP8
#undef ISSUE8
#undef CONSUME8
}

// ---------------------------------------------------------------------------
// Kernel 3: broadcast row 0 -> rows 1..B-1 (spikes + membrane).
// RESTRUCTURED: 125x8 blocks; each thread loads its row-0 vf4 pair ONCE and
// streams up to 128 rows of nontemporal stores (was 32k blocks x 8 stores).
// ---------------------------------------------------------------------------
#define BROWS 128  // rows per y-block

__global__ void bcast_kernel(float* __restrict__ out,
                             long long TN4, long long B_TN, int B) {
    const long long i = (long long)blockIdx.x * blockDim.x + threadIdx.x;
    if (i >= TN4) return;
    const vf4 vs = ((const vf4*)out)[i];
    const vf4 vm = ((const vf4*)(out + B_TN))[i];
    vf4* dsp = (vf4*)out;
    vf4* dme = (vf4*)(out + B_TN);
    const int b0 = 1 + (int)blockIdx.y * BROWS;
    int b1 = b0 + BROWS;
    if (b1 > B) b1 = B;
    for (int b = b0; b < b1; ++b) {
        __builtin_nontemporal_store(vs, dsp + (long long)b * TN4 + i);
        __builtin_nontemporal_store(vm, dme + (long long)b * TN4 + i);
    }
}

// ---------------------------------------------------------------------------
// Kernel 4: broadcast final trace row 0 -> rows 1..B-1. UNCHANGED.
// ---------------------------------------------------------------------------
__global__ void trace_bcast_kernel(float* __restrict__ tr, int B, int N4) {
    const int idx = blockIdx.x * blockDim.x + threadIdx.x;
    const int total = (B - 1) * N4;
    if (idx >= total) return;
    const int b = idx / N4 + 1;
    const int j = idx - (b - 1) * N4;
    const vf4 v = ((const vf4*)tr)[j];
    __builtin_nontemporal_store(v, &((vf4*)(tr + (size_t)b * N4 * 4))[j]);
}

// ---------------------------------------------------------------------------
extern "C" void kernel_launch(void* const* d_in, const int* in_sizes, int n_in,
                              void* d_out, int out_size, void* d_ws, size_t ws_size,
                              hipStream_t stream) {
    const float* sig  = (const float*)d_in[0];  // (T, D)
    const float* win  = (const float*)d_in[1];  // (D, N)
    const float* wrec = (const float*)d_in[2];  // (N, N)

    int N = 1;
    while ((long long)N * N < (long long)in_sizes[2]) ++N;   // N = 128
    const int D = in_sizes[1] / N;                            // 64
    const int B = in_sizes[0] / D;                            // 1000 (= T)
    const int nt = (int)((((long long)out_size / B) - N) / (2 * N));  // 1000

    const long long TN   = (long long)nt * N;   // 128,000
    const long long B_TN = (long long)B * TN;   // 128,000,000

    float* out = (float*)d_out;
    // f64 inp_cur scratch in the tail of d_out (= membrane row B-1 + trace),
    // consumed by sim before bcast/trace_bcast overwrite it (stream order).
    double* inp_cur = (double*)(out + ((size_t)out_size - 2 * (size_t)TN));

    inpcur_kernel<<<nt, N, 0, stream>>>(sig, win, inp_cur, D, N);

    sim_kernel<<<1, 64, 0, stream>>>(inp_cur, wrec,
                                     out,              // spikes row 0
                                     out + B_TN,       // membrane row 0
                                     out + 2 * B_TN,   // trace row 0
                                     nt);

    const long long TN4 = TN / 4;                    // 32,000
    dim3 bgrid((unsigned)((TN4 + 255) / 256), (unsigned)((B - 1 + BROWS - 1) / BROWS));
    bcast_kernel<<<bgrid, 256, 0, stream>>>(out, TN4, B_TN, B);

    const int trace_total = (B - 1) * (N / 4);
    trace_bcast_kernel<<<(trace_total + 255) / 256, 256, 0, stream>>>(
        out + 2 * B_TN, B, N / 4);
}

// Round 11
// 1950.958 us; speedup vs baseline: 1.1688x; 1.1688x over previous
//
#include <hip/hip_runtime.h>
#include <math.h>

// B = T = 1000, N = 128, D = 64. All batch rows identical; f64 trajectory is
// deterministic. Round 11: REPLICATED SIM — 250 independent blocks each
// recompute the identical 1000-step scan (round-9 body verbatim, proven
// 1040-1080us) and write 4 batch rows directly (rows j, j+250, j+500, j+750).
// This deletes the ~970us broadcast pass (measured ~1.1 TB/s ceiling) by
// spreading the 1.02GB of writes across the sim's own latency-bound runtime.
// Round-10 sim experiment (branchy pipelined gather) regressed 1050->1265us
// (VALUBusy 0.039->0.026: stalls grew) -> reverted to round-9 body.
// inp_cur scratch moved to membrane rows B-3,B-2 (exact 1MB fit): no block
// writes those rows during the sim; fixup kernel copies them afterward.

#define XCHUNK 8   // input-current register prefetch depth (steps)
#define NBLK   250 // sim replicas; each owns rows j + k*NBLK, k=0..3

typedef float vf4 __attribute__((ext_vector_type(4)));  // clang-native float4

// ---------------------------------------------------------------------------
// Kernel 1: inp_cur[t][n] = sum_d sig[t][d] * win[d][n]  (float64 accumulate)
// UNCHANGED numerics (bit-exact reproducibility).
// ---------------------------------------------------------------------------
__global__ void inpcur_kernel(const float* __restrict__ sig,
                              const float* __restrict__ win,
                              double* __restrict__ inp_cur,
                              int D, int N) {
    const int t = blockIdx.x;
    const int n = threadIdx.x;
    const float* srow = sig + (size_t)t * D;
    double acc = 0.0;
    for (int d = 0; d < D; ++d)
        acc += (double)srow[d] * (double)win[(size_t)d * N + n];
    inp_cur[(size_t)t * N + n] = acc;
}

// ---------------------------------------------------------------------------
// Kernel 2: replicated 1000-step LIF scan. ONE wave per block; every block
// computes the identical trajectory (round-9 body: lane l owns neurons l and
// l+64, batch-8 branchless gather, /10.0) and streams its 4 rows of output.
// Membrane rows B-3 and B-2 are skipped (they hold the inp_cur scratch).
// ---------------------------------------------------------------------------
__global__ __launch_bounds__(64, 1) void simrep_kernel(
    const double* __restrict__ inp_cur,
    const float* __restrict__ wrec,
    float* __restrict__ out,      // full output base
    long long TN, long long B_TN, int B, int nt) {
    __shared__ float lds_w[128 * 128];  // 64 KiB: wrec row-major

    const int l = threadIdx.x;  // lane 0..63
    const int j = blockIdx.x;   // replica id 0..NBLK-1

    __builtin_amdgcn_s_setprio(3);

    // Per-block output row bases (wave-uniform -> SGPRs).
    float* spk[4];
    float* mem[4];
    bool   wmem[4];
    int    rows[4];
    #pragma unroll
    for (int k = 0; k < 4; ++k) {
        rows[k] = j + k * NBLK;                    // covers 0..999 bijectively
        spk[k]  = out + (long long)rows[k] * TN;
        mem[k]  = out + B_TN + (long long)rows[k] * TN;
        wmem[k] = (rows[k] != B - 3) && (rows[k] != B - 2);  // scratch rows
    }
    float* trace = out + 2 * B_TN;

    // Stage wrec into LDS: 16384 floats, float4-vectorized, coalesced.
    {
        const vf4* src = (const vf4*)wrec;
        vf4* dst = (vf4*)lds_w;
        for (int i = 0; i < 64; ++i)
            dst[i * 64 + l] = src[i * 64 + l];
        // Same-wave LDS RAW handled by compiler waitcnt; no barrier needed.
    }

    double mem_lo = 0.0, syn_lo = 0.0, trc_lo = 0.0, refr_lo = 0.0, rec_lo = 0.0;
    double mem_hi = 0.0, syn_hi = 0.0, trc_hi = 0.0, refr_hi = 0.0, rec_hi = 0.0;

    double x_lo[XCHUNK], x_hi[XCHUNK];

    for (int t0 = 0; t0 < nt; t0 += XCHUNK) {
        const int cs = (nt - t0 < XCHUNK) ? (nt - t0) : XCHUNK;
        // Prefetch cs steps of input current: 2*cs independent loads, one wait.
        #pragma unroll
        for (int s = 0; s < XCHUNK; ++s) {
            if (s < cs) {
                x_lo[s] = inp_cur[(size_t)(t0 + s) * 128 + l];
                x_hi[s] = inp_cur[(size_t)(t0 + s) * 128 + l + 64];
            }
        }

        #pragma unroll
        for (int s = 0; s < XCHUNK; ++s) {
            if (s >= cs) break;
            const int t = t0 + s;

            syn_lo = syn_lo * (1.0 - 1.0 / 5.0) + x_lo[s] + rec_lo;
            mem_lo = mem_lo * (1.0 - 1.0 / 10.0) + syn_lo / 10.0;
            if (refr_lo > 0.0) mem_lo = 0.0;
            refr_lo = refr_lo - 1.0;
            if (refr_lo < 0.0) refr_lo = 0.0;
            const bool sp_lo = mem_lo > 1.0;

            syn_hi = syn_hi * (1.0 - 1.0 / 5.0) + x_hi[s] + rec_hi;
            mem_hi = mem_hi * (1.0 - 1.0 / 10.0) + syn_hi / 10.0;
            if (refr_hi > 0.0) mem_hi = 0.0;
            refr_hi = refr_hi - 1.0;
            if (refr_hi < 0.0) refr_hi = 0.0;
            const bool sp_hi = mem_hi > 1.0;

            // Wave-uniform spike masks (rows 0-63 and 64-127), in SGPRs.
            const unsigned long long m0 = __ballot(sp_lo);
            const unsigned long long m1 = __ballot(sp_hi);

            if (sp_lo) { mem_lo = 0.0; refr_lo += 2.0; }
            trc_lo = trc_lo * 0.95 + (sp_lo ? 1.0 : 0.0);
            if (sp_hi) { mem_hi = 0.0; refr_hi += 2.0; }
            trc_hi = trc_hi * 0.95 + (sp_hi ? 1.0 : 0.0);

            // Stream this step's outputs for all 4 owned rows (nontemporal:
            // 1GB total, keep L2 for inp_cur/wrec). Fire-and-forget.
            {
                const float s0f = sp_lo ? 1.0f : 0.0f;
                const float s1f = sp_hi ? 1.0f : 0.0f;
                const float m0f = (float)mem_lo;
                const float m1f = (float)mem_hi;
                #pragma unroll
                for (int k = 0; k < 4; ++k) {
                    __builtin_nontemporal_store(s0f, &spk[k][(size_t)t * 128 + l]);
                    __builtin_nontemporal_store(s1f, &spk[k][(size_t)t * 128 + l + 64]);
                    if (wmem[k]) {
                        __builtin_nontemporal_store(m0f, &mem[k][(size_t)t * 128 + l]);
                        __builtin_nontemporal_store(m1f, &mem[k][(size_t)t * 128 + l + 64]);
                    }
                }
            }

            // Sparse recurrent gather: rows ascending (m0 then m1), batches
            // of 8 so 16 LDS reads are in flight before one wait. Padded
            // slots add exact +0.0 (bit-identical f64 sum). ROUND-9 VERBATIM.
            double add_lo = 0.0, add_hi = 0.0;
            #pragma unroll 1
            for (int half = 0; half < 2; ++half) {
                unsigned long long m = half ? m1 : m0;
                const float* wb = lds_w + (half ? (64 * 128) : 0);
                while (m) {
                    int kk[8];
                    bool vv[8];
                    #pragma unroll
                    for (int jj = 0; jj < 8; ++jj) {
                        vv[jj] = (m != 0ull);
                        kk[jj] = m ? (int)__builtin_ctzll(m) : 0;
                        m &= (m - 1ull);
                    }
                    float wl[8], wh[8];
                    #pragma unroll
                    for (int jj = 0; jj < 8; ++jj) {
                        wl[jj] = wb[kk[jj] * 128 + l];
                        wh[jj] = wb[kk[jj] * 128 + l + 64];
                    }
                    #pragma unroll
                    for (int jj = 0; jj < 8; ++jj) {
                        add_lo += vv[jj] ? (double)wl[jj] : 0.0;
                        add_hi += vv[jj] ? (double)wh[jj] : 0.0;
                    }
                }
            }
            rec_lo = rec_lo * 0.95 + add_lo;
            rec_hi = rec_hi * 0.95 + add_hi;
        }
    }

    // Final trace for all owned rows (trace region does not overlap scratch).
    #pragma unroll
    for (int k = 0; k < 4; ++k) {
        trace[(size_t)rows[k] * 128 + l]      = (float)trc_lo;
        trace[(size_t)rows[k] * 128 + l + 64] = (float)trc_hi;
    }
}

// ---------------------------------------------------------------------------
// Kernel 3: fixup — copy membrane row 0 over the scratch rows B-3, B-2
// (runs after simrep in stream order; scratch fully consumed by then).
// ---------------------------------------------------------------------------
__global__ void fixup_kernel(float* __restrict__ mem_base, long long TN,
                             int rowA, int rowB) {
    const long long tn4 = TN / 4;
    const long long idx = (long long)blockIdx.x * blockDim.x + threadIdx.x;
    if (idx >= 2 * tn4) return;
    const int r = (idx < tn4) ? rowA : rowB;
    const long long i = (idx < tn4) ? idx : idx - tn4;
    const vf4 v = ((const vf4*)mem_base)[i];
    __builtin_nontemporal_store(v, (vf4*)mem_base + (long long)r * tn4 + i);
}

// ---------------------------------------------------------------------------
extern "C" void kernel_launch(void* const* d_in, const int* in_sizes, int n_in,
                              void* d_out, int out_size, void* d_ws, size_t ws_size,
                              hipStream_t stream) {
    const float* sig  = (const float*)d_in[0];  // (T, D)
    const float* win  = (const float*)d_in[1];  // (D, N)
    const float* wrec = (const float*)d_in[2];  // (N, N)

    int N = 1;
    while ((long long)N * N < (long long)in_sizes[2]) ++N;   // N = 128
    const int D = in_sizes[1] / N;                            // 64
    const int B = in_sizes[0] / D;                            // 1000 (= T)
    const int nt = (int)((((long long)out_size / B) - N) / (2 * N));  // 1000

    const long long TN   = (long long)nt * N;   // 128,000
    const long long B_TN = (long long)B * TN;   // 128,000,000

    float* out = (float*)d_out;
    // f64 inp_cur scratch = membrane rows B-3, B-2 (exactly nt*N doubles).
    // simrep never writes those rows; fixup restores them afterward.
    double* inp_cur = (double*)(out + B_TN + (long long)(B - 3) * TN);

    inpcur_kernel<<<nt, N, 0, stream>>>(sig, win, inp_cur, D, N);

    simrep_kernel<<<NBLK, 64, 0, stream>>>(inp_cur, wrec, out,
                                           TN, B_TN, B, nt);

    const long long tn4 = TN / 4;
    fixup_kernel<<<(unsigned)((2 * tn4 + 255) / 256), 256, 0, stream>>>(
        out + B_TN, TN, B - 3, B - 2);
}